// Round 11
// baseline (148.979 us; speedup 1.0000x reference)
//
#include <hip/hip_runtime.h>
#include <math.h>

using short8   = __attribute__((ext_vector_type(8))) short;
using floatx4  = __attribute__((ext_vector_type(4))) float;
using ushort4v = __attribute__((ext_vector_type(4))) unsigned short;

__device__ __forceinline__ unsigned short f2bf(float x) {
  union { float f; unsigned u; } v; v.f = x;
  unsigned r = (v.u + 0x7FFFu + ((v.u >> 16) & 1u)) >> 16;
  return (unsigned short)r;
}
__device__ __forceinline__ float bf2f(unsigned short u) {
  union { unsigned u; float f; } v; v.u = ((unsigned)u) << 16;
  return v.f;
}
__device__ __forceinline__ short8 pack_a(int4 v0, int4 v1) {
  union { uint4 u; short8 s; } r;
  r.u.x = ((unsigned)v0.x | ((unsigned)v0.y << 16)) * 0x3F80u;
  r.u.y = ((unsigned)v0.z | ((unsigned)v0.w << 16)) * 0x3F80u;
  r.u.z = ((unsigned)v1.x | ((unsigned)v1.y << 16)) * 0x3F80u;
  r.u.w = ((unsigned)v1.z | ((unsigned)v1.w << 16)) * 0x3F80u;
  return r.s;
}

// ---------------- K1: Wh = h @ W (f32, bf16 out) + fused g-dot epilogue ----------------
__global__ __launch_bounds__(256) void wh_gemm(
    const float* __restrict__ h, const float* __restrict__ W,
    unsigned short* __restrict__ Whb, const float* __restrict__ a,
    float* __restrict__ g) {
  __shared__ __align__(16) float Al[16][64];
  __shared__ __align__(16) float Bl[16][128];
  const int m0 = blockIdx.x * 64;
  const int n0 = blockIdx.y * 128;
  const int t  = threadIdx.x;
  const int tx = t & 15, ty = t >> 4;
  float acc[4][8];
#pragma unroll
  for (int i = 0; i < 4; ++i)
#pragma unroll
    for (int j = 0; j < 8; ++j) acc[i][j] = 0.0f;

  for (int k0 = 0; k0 < 256; k0 += 16) {
    {
      int m = t & 63, kq = t >> 6;
      float4 v = *(const float4*)&h[(size_t)(m0 + m) * 256 + k0 + kq * 4];
      Al[kq * 4 + 0][m] = v.x; Al[kq * 4 + 1][m] = v.y;
      Al[kq * 4 + 2][m] = v.z; Al[kq * 4 + 3][m] = v.w;
    }
    {
      int n4 = t & 31, kr = t >> 5;
      *(float4*)&Bl[kr][n4 * 4]     = *(const float4*)&W[(size_t)(k0 + kr) * 256 + n0 + n4 * 4];
      *(float4*)&Bl[kr + 8][n4 * 4] = *(const float4*)&W[(size_t)(k0 + kr + 8) * 256 + n0 + n4 * 4];
    }
    __syncthreads();
#pragma unroll
    for (int k = 0; k < 16; ++k) {
      float4 av = *(const float4*)&Al[k][ty * 4];
      float4 b0 = *(const float4*)&Bl[k][tx * 4];
      float4 b1 = *(const float4*)&Bl[k][64 + tx * 4];
      float aa[4] = {av.x, av.y, av.z, av.w};
      float bb[8] = {b0.x, b0.y, b0.z, b0.w, b1.x, b1.y, b1.z, b1.w};
#pragma unroll
      for (int i = 0; i < 4; ++i)
#pragma unroll
        for (int j = 0; j < 8; ++j) acc[i][j] = fmaf(aa[i], bb[j], acc[i][j]);
    }
    __syncthreads();
  }
  float4 a2lo = *(const float4*)&a[256 + n0 + tx * 4];
  float4 a2hi = *(const float4*)&a[256 + n0 + 64 + tx * 4];
#pragma unroll
  for (int i = 0; i < 4; ++i) {
    size_t row = (size_t)(m0 + ty * 4 + i);
    ushort4v o0, o1;
#pragma unroll
    for (int j = 0; j < 4; ++j) { o0[j] = f2bf(acc[i][j]); o1[j] = f2bf(acc[i][4 + j]); }
    *(ushort4v*)&Whb[row * 256 + n0 + tx * 4]      = o0;
    *(ushort4v*)&Whb[row * 256 + n0 + 64 + tx * 4] = o1;
    float p = acc[i][0] * a2lo.x + acc[i][1] * a2lo.y + acc[i][2] * a2lo.z + acc[i][3] * a2lo.w
            + acc[i][4] * a2hi.x + acc[i][5] * a2hi.y + acc[i][6] * a2hi.z + acc[i][7] * a2hi.w;
#pragma unroll
    for (int off = 1; off < 16; off <<= 1) p += __shfl_xor(p, off);
    if (tx == 0) atomicAdd(&g[row], p);
  }
}

// ---------------- K2b: per-batch max of g ----------------
__global__ __launch_bounds__(256) void batch_max(
    const float* __restrict__ g, float* __restrict__ Mb) {
  __shared__ float red[4];
  int b = blockIdx.x, t = threadIdx.x;
  float m = -1e30f;
  for (int i = t; i < 2048; i += 256) m = fmaxf(m, g[(size_t)b * 2048 + i]);
#pragma unroll
  for (int off = 32; off > 0; off >>= 1) m = fmaxf(m, __shfl_xor(m, off));
  if ((t & 63) == 0) red[t >> 6] = m;
  __syncthreads();
  if (t == 0) Mb[b] = fmaxf(fmaxf(red[0], red[1]), fmaxf(red[2], red[3]));
}

// ---------------- K2c: tile-contiguous B (row-padded LDS: 64->72 shorts kills
// the 8-way read conflict; rows at 144B => 2-way max, free) ----------------
__global__ __launch_bounds__(256) void build_bt(
    const unsigned short* __restrict__ Whb, const float* __restrict__ g,
    const float* __restrict__ Mb, unsigned short* __restrict__ Bt) {
  __shared__ __align__(16) unsigned short tile[320 * 72];  // [c][j], j-pad to 72
  const int blk = blockIdx.x;
  const int b   = blk >> 5;
  const int j0  = (blk & 31) * 64;
  const int kt_base = (blk & 31) * 2;
  const int t   = threadIdx.x;
  const int j   = t & 63;
  const int q0  = t >> 6;
  const int row = b * 2048 + j0 + j;
  const float s = expf(g[row] - Mb[b]);
  for (int q = q0; q < 64; q += 4) {
    ushort4v wv = *(const ushort4v*)&Whb[(size_t)row * 256 + q * 4];
    int c = q * 4;
    tile[(c + 0) * 72 + j] = f2bf(s * bf2f(wv[0]));
    tile[(c + 1) * 72 + j] = f2bf(s * bf2f(wv[1]));
    tile[(c + 2) * 72 + j] = f2bf(s * bf2f(wv[2]));
    tile[(c + 3) * 72 + j] = f2bf(s * bf2f(wv[3]));
  }
  if (q0 == 0) tile[256 * 72 + j] = f2bf(s);
  for (int z = t; z < 63 * 64; z += 256) {
    int c = 257 + (z >> 6);
    tile[c * 72 + (z & 63)] = 0;
  }
  __syncthreads();
#pragma unroll
  for (int p = 0; p < 10; ++p) {
    int id = t + 256 * p;          // 0..2559 -> (c, off)
    int c = id >> 3, off = id & 7;
    int kt_l = off >> 2, slot = off & 3;
    size_t dst = ((size_t)((b * 64 + kt_base + kt_l) * 320 + c)) * 64 + (slot << 4);
    *(int4*)((char*)Bt + dst) = *(const int4*)&tile[c * 72 + off * 8];
  }
}

// ---------------- K3: [num|den] = adj @ Bt^T, barrier-free, raw-adj A-path ----------------
// grid 256 (b=bid&7 XCD-pinned), 512 threads = 8 waves (2 row-grp x 4 col-grp).
// BM=64, BN=320. BOTH operands direct global->reg: A = 4 int4/lane from raw adj
// (wave covers 16 rows x 128B contiguous), B = 5 short8/lane from L2-resident Bt.
// 4 named sets (9 vm-ops each), vmcnt(27) gates (tail 27/18/9/0). No LDS, no
// barriers in the K-loop; gat_main is now the single 134MB adj reader.
__global__ __launch_bounds__(512, 2) void gat_main(
    const int* __restrict__ adj, const unsigned short* __restrict__ Bt,
    float* __restrict__ out) {
  __shared__ float denL[64];
  const int bid = blockIdx.x;
  const int b   = bid & 7;
  const int rb  = bid >> 3;
  const int i0  = rb * 64;
  const int tid = threadIdx.x;
  const int w   = tid >> 6, L = tid & 63;
  const int wm  = w >> 2, wn = w & 3;     // row-group, col-group
  const int fr  = L & 15, kc = L >> 4;

  // A per-lane source: row = i0 + wm*32 + mf*16 + fr, bytes kt*128 + kc*32 (+16)
  const char* asrc = (const char*)adj + ((size_t)b * 2048 + i0 + wm * 32 + fr) * 8192
                   + kc * 32;
  // B per-lane source: col = wn*80 + nf*16 + fr, k-slot kc
  const char* bsrc = (const char*)Bt + (size_t)b * 1310720
                   + (size_t)(wn * 80 + fr) * 64 + (kc << 4);

  floatx4 acc[2][5];
#pragma unroll
  for (int i = 0; i < 2; ++i)
#pragma unroll
    for (int n = 0; n < 5; ++n) acc[i][n] = (floatx4)0.0f;

  int4   a0[4], a1[4], a2[4], a3[4];
  short8 b0[5], b1[5], b2[5], b3[5];

#define LOADSET(TT, A, B) {                               \
    const char* ap_ = asrc + (size_t)(TT) * 128;          \
    A[0] = *(const int4*)(ap_);                           \
    A[1] = *(const int4*)(ap_ + 16);                      \
    A[2] = *(const int4*)(ap_ + 131072);                  \
    A[3] = *(const int4*)(ap_ + 131072 + 16);             \
    const char* bp_ = bsrc + (size_t)(TT) * 20480;        \
    B[0] = *(const short8*)(bp_);                         \
    B[1] = *(const short8*)(bp_ + 1024);                  \
    B[2] = *(const short8*)(bp_ + 2048);                  \
    B[3] = *(const short8*)(bp_ + 3072);                  \
    B[4] = *(const short8*)(bp_ + 4096);                  \
  }

#define COMPUTE(A, B) {                                                          \
    short8 af0_ = pack_a(A[0], A[1]);                                            \
    short8 af1_ = pack_a(A[2], A[3]);                                            \
    _Pragma("unroll")                                                            \
    for (int nf = 0; nf < 5; ++nf) {                                             \
      acc[0][nf] = __builtin_amdgcn_mfma_f32_16x16x32_bf16(af0_, B[nf], acc[0][nf], 0, 0, 0); \
      acc[1][nf] = __builtin_amdgcn_mfma_f32_16x16x32_bf16(af1_, B[nf], acc[1][nf], 0, 0, 0); \
    }                                                                            \
  }

#define PHASE(LTT, LA, LB, CA, CB) {                       \
    LOADSET(LTT, LA, LB);                                  \
    asm volatile("s_waitcnt vmcnt(27)" ::: "memory");      \
    COMPUTE(CA, CB);                                       \
  }

#define TAILPHASE(GATE, CA, CB) {                          \
    asm volatile("s_waitcnt vmcnt(" #GATE ")" ::: "memory"); \
    COMPUTE(CA, CB);                                       \
  }

  LOADSET(0, a0, b0); LOADSET(1, a1, b1); LOADSET(2, a2, b2);

#pragma unroll 1
  for (int k = 0; k < 15; ++k) {
    int t4 = k * 4;
    PHASE(t4 + 3, a3, b3, a0, b0);
    PHASE(t4 + 4, a0, b0, a1, b1);
    PHASE(t4 + 5, a1, b1, a2, b2);
    PHASE(t4 + 6, a2, b2, a3, b3);
  }
  // tiles 60..63 in sets 0..3
  LOADSET(63, a3, b3);
  TAILPHASE(27, a0, b0);
  TAILPHASE(18, a1, b1);
  TAILPHASE(9,  a2, b2);
  TAILPHASE(0,  a3, b3);

  // epilogue: den = col 256 -> wn==3, nf==1, fr==0
  const int q = L >> 4;
  if (wn == 3 && fr == 0) {
#pragma unroll
    for (int mf = 0; mf < 2; ++mf)
#pragma unroll
      for (int jj = 0; jj < 4; ++jj)
        denL[wm * 32 + mf * 16 + q * 4 + jj] = acc[mf][1][jj];
  }
  __syncthreads();
  float invd[2][4];
#pragma unroll
  for (int mf = 0; mf < 2; ++mf)
#pragma unroll
    for (int jj = 0; jj < 4; ++jj)
      invd[mf][jj] = 1.0f / denL[wm * 32 + mf * 16 + q * 4 + jj];
#pragma unroll
  for (int mf = 0; mf < 2; ++mf) {
#pragma unroll
    for (int nf = 0; nf < 5; ++nf) {
      int col = wn * 80 + nf * 16 + fr;
      if (col < 256) {
#pragma unroll
        for (int jj = 0; jj < 4; ++jj) {
          int row = wm * 32 + mf * 16 + q * 4 + jj;
          float v = acc[mf][nf][jj] * invd[mf][jj];
          v = (v > 0.0f) ? v : expm1f(v);
          out[((size_t)b * 2048 + i0 + row) * 256 + col] = v;
        }
      }
    }
  }
#undef PHASE
#undef TAILPHASE
#undef COMPUTE
#undef LOADSET
}

extern "C" void kernel_launch(void* const* d_in, const int* in_sizes, int n_in,
                              void* d_out, int out_size, void* d_ws, size_t ws_size,
                              hipStream_t stream) {
  const float* h   = (const float*)d_in[0];
  const int*   adj = (const int*)d_in[1];
  const float* W   = (const float*)d_in[2];
  const float* a   = (const float*)d_in[3];
  float* out = (float*)d_out;

  char* ws = (char*)d_ws;
  if (ws_size < 18940160) return;
  unsigned short* Whb = (unsigned short*)ws;              //  8,388,608 B
  float* g            = (float*)(ws + 8388608);           //     65,536 B
  float* Mb           = (float*)(ws + 8454144);           //        256 B
  unsigned short* Bt  = (unsigned short*)(ws + 8454400);  // 10,485,760 B

  hipMemsetAsync(g, 0, 65536, stream);
  wh_gemm  <<<dim3(256, 2), 256, 0, stream>>>(h, W, Whb, a, g);
  batch_max<<<8,           256, 0, stream>>>(g, Mb);
  build_bt <<<256,         256, 0, stream>>>(Whb, g, Mb, Bt);
  gat_main <<<256,         512, 0, stream>>>(adj, Bt, out);
}

// Round 12
// 113.955 us; speedup vs baseline: 1.3073x; 1.3073x over previous
//
#include <hip/hip_runtime.h>
#include <math.h>

using short8   = __attribute__((ext_vector_type(8))) short;
using floatx4  = __attribute__((ext_vector_type(4))) float;
using ushort4v = __attribute__((ext_vector_type(4))) unsigned short;

__device__ __forceinline__ unsigned short f2bf(float x) {
  union { float f; unsigned u; } v; v.f = x;
  unsigned r = (v.u + 0x7FFFu + ((v.u >> 16) & 1u)) >> 16;
  return (unsigned short)r;
}
__device__ __forceinline__ float bf2f(unsigned short u) {
  union { unsigned u; float f; } v; v.u = ((unsigned)u) << 16;
  return v.f;
}
__device__ __forceinline__ short8 cvt8(const float* p) {
  float4 v0 = *(const float4*)p;
  float4 v1 = *(const float4*)(p + 4);
  short8 r;
  r[0] = (short)f2bf(v0.x); r[1] = (short)f2bf(v0.y);
  r[2] = (short)f2bf(v0.z); r[3] = (short)f2bf(v0.w);
  r[4] = (short)f2bf(v1.x); r[5] = (short)f2bf(v1.y);
  r[6] = (short)f2bf(v1.z); r[7] = (short)f2bf(v1.w);
  return r;
}

// ---------------- K0: W (f32 [k][n]) -> Wt bf16 tile layout ----------------
// Wt[(kt*256 + c)*32 + (k&31)] = bf16(W[k][c]), kt = k>>5.
__global__ __launch_bounds__(256) void wt_conv(
    const float* __restrict__ W, unsigned short* __restrict__ Wt) {
  int c = blockIdx.x;
  int k = threadIdx.x;
  int kt = k >> 5;
  Wt[(size_t)(kt * 256 + c) * 32 + (k & 31)] = f2bf(W[(size_t)k * 256 + c]);
}

// ---------------- K1: Wh = h @ W via bf16 MFMA (f32 accum) + fused g-dot ----------------
// grid 512 (BM=32), 256 threads = 4 waves; wave w covers cols w*64..+63.
__global__ __launch_bounds__(256) void wh_mfma(
    const float* __restrict__ h, const unsigned short* __restrict__ Wt,
    unsigned short* __restrict__ Whb, const float* __restrict__ a,
    float* __restrict__ g) {
  const int m0 = blockIdx.x * 32;
  const int t  = threadIdx.x;
  const int w  = t >> 6, L = t & 63;
  const int fr = L & 15, kc = L >> 4;

  const float* hrow0 = h + (size_t)(m0 + fr) * 256;
  const float* hrow1 = h + (size_t)(m0 + 16 + fr) * 256;

  floatx4 acc[2][4];
#pragma unroll
  for (int i = 0; i < 2; ++i)
#pragma unroll
    for (int n = 0; n < 4; ++n) acc[i][n] = (floatx4)0.0f;

#pragma unroll
  for (int kt = 0; kt < 8; ++kt) {
    short8 a0 = cvt8(hrow0 + kt * 32 + kc * 8);
    short8 a1 = cvt8(hrow1 + kt * 32 + kc * 8);
#pragma unroll
    for (int nf = 0; nf < 4; ++nf) {
      int c = w * 64 + nf * 16 + fr;
      short8 bf = *(const short8*)(Wt + (size_t)(kt * 256 + c) * 32 + kc * 8);
      acc[0][nf] = __builtin_amdgcn_mfma_f32_16x16x32_bf16(a0, bf, acc[0][nf], 0, 0, 0);
      acc[1][nf] = __builtin_amdgcn_mfma_f32_16x16x32_bf16(a1, bf, acc[1][nf], 0, 0, 0);
    }
  }

  // epilogue: store Whb bf16 + g-dot (g pre-zeroed)
  const int q = L >> 4;
  float a2v[4];
#pragma unroll
  for (int nf = 0; nf < 4; ++nf) a2v[nf] = a[256 + w * 64 + nf * 16 + fr];
#pragma unroll
  for (int mf = 0; mf < 2; ++mf) {
    float p[4] = {0.f, 0.f, 0.f, 0.f};
#pragma unroll
    for (int nf = 0; nf < 4; ++nf) {
#pragma unroll
      for (int jj = 0; jj < 4; ++jj) {
        int row = m0 + mf * 16 + q * 4 + jj;
        Whb[(size_t)row * 256 + w * 64 + nf * 16 + fr] = f2bf(acc[mf][nf][jj]);
        p[jj] += acc[mf][nf][jj] * a2v[nf];
      }
    }
#pragma unroll
    for (int jj = 0; jj < 4; ++jj) {
#pragma unroll
      for (int off = 1; off < 16; off <<= 1) p[jj] += __shfl_xor(p[jj], off);
      if (fr == 0) atomicAdd(&g[m0 + mf * 16 + q * 4 + jj], p[jj]);
    }
  }
}

// ---------------- K2b: per-batch max of g ----------------
__global__ __launch_bounds__(256) void batch_max(
    const float* __restrict__ g, float* __restrict__ Mb) {
  __shared__ float red[4];
  int b = blockIdx.x, t = threadIdx.x;
  float m = -1e30f;
  for (int i = t; i < 2048; i += 256) m = fmaxf(m, g[(size_t)b * 2048 + i]);
#pragma unroll
  for (int off = 32; off > 0; off >>= 1) m = fmaxf(m, __shfl_xor(m, off));
  if ((t & 63) == 0) red[t >> 6] = m;
  __syncthreads();
  if (t == 0) Mb[b] = fmaxf(fmaxf(red[0], red[1]), fmaxf(red[2], red[3]));
}

// ---------------- K2c: tile-contiguous B (72-short padded rows) ----------------
__global__ __launch_bounds__(256) void build_bt(
    const unsigned short* __restrict__ Whb, const float* __restrict__ g,
    const float* __restrict__ Mb, unsigned short* __restrict__ Bt) {
  __shared__ __align__(16) unsigned short tile[320 * 72];
  const int blk = blockIdx.x;
  const int b   = blk >> 5;
  const int j0  = (blk & 31) * 64;
  const int kt_base = (blk & 31) * 2;
  const int t   = threadIdx.x;
  const int j   = t & 63;
  const int q0  = t >> 6;
  const int row = b * 2048 + j0 + j;
  const float s = expf(g[row] - Mb[b]);
  for (int q = q0; q < 64; q += 4) {
    ushort4v wv = *(const ushort4v*)&Whb[(size_t)row * 256 + q * 4];
    int c = q * 4;
    tile[(c + 0) * 72 + j] = f2bf(s * bf2f(wv[0]));
    tile[(c + 1) * 72 + j] = f2bf(s * bf2f(wv[1]));
    tile[(c + 2) * 72 + j] = f2bf(s * bf2f(wv[2]));
    tile[(c + 3) * 72 + j] = f2bf(s * bf2f(wv[3]));
  }
  if (q0 == 0) tile[256 * 72 + j] = f2bf(s);
  for (int z = t; z < 63 * 64; z += 256) {
    int c = 257 + (z >> 6);
    tile[c * 72 + (z & 63)] = 0;
  }
  __syncthreads();
#pragma unroll
  for (int p = 0; p < 10; ++p) {
    int id = t + 256 * p;
    int c = id >> 3, off = id & 7;
    int kt_l = off >> 2, slot = off & 3;
    size_t dst = ((size_t)((b * 64 + kt_base + kt_l) * 320 + c)) * 64 + (slot << 4);
    *(int4*)((char*)Bt + dst) = *(const int4*)&tile[c * 72 + off * 8];
  }
}

// ---------------- K3: [num|den] = adj @ Bt^T ----------------
// R8-proven K-loop (LDS bit-A + 5 B named sets + vmcnt(20), launch_bounds(512,2)).
// NEW: prologue reads RAW adj (64 rows x 8KB) and packs bits in-register ->
// LDS, removing the separate adj_pack pass entirely.
__global__ __launch_bounds__(512, 2) void gat_main(
    const int* __restrict__ adj, const unsigned short* __restrict__ Bt,
    float* __restrict__ out) {
  __shared__ __align__(16) char lds[64 * 272 + 256];  // A bits (stride 272) + den
  const int bid = blockIdx.x;
  const int b   = bid & 7;
  const int rb  = bid >> 3;
  const int i0  = rb * 64;
  const int tid = threadIdx.x;
  const int w   = tid >> 6, L = tid & 63;
  const int wm  = w >> 2, wn = w & 3;
  const int fr  = L & 15, kc = L >> 4;

  // prologue: read raw adj, pack 1 bit/int, write 64x256B bit rows (stride 272)
  {
    int r = tid >> 3, seg = tid & 7;
    const int* src = adj + ((size_t)b * 2048 + i0 + r) * 2048 + seg * 256;
    unsigned wds[8];
#pragma unroll
    for (int wl = 0; wl < 8; ++wl) {
      unsigned rr = 0;
#pragma unroll
      for (int q = 0; q < 8; ++q) {
        int4 v = *(const int4*)(src + wl * 32 + q * 4);
        rr |= ((unsigned)v.x << (4 * q)) | ((unsigned)v.y << (4 * q + 1)) |
              ((unsigned)v.z << (4 * q + 2)) | ((unsigned)v.w << (4 * q + 3));
      }
      wds[wl] = rr;
    }
    char* dst = lds + r * 272 + seg * 32;
    *(int4*)(dst)      = make_int4(wds[0], wds[1], wds[2], wds[3]);
    *(int4*)(dst + 16) = make_int4(wds[4], wds[5], wds[6], wds[7]);
  }
  __syncthreads();

  const char* bsrc = (const char*)Bt + (size_t)b * 1310720
                   + (size_t)(wn * 80 + fr) * 64 + (kc << 4);
  const char* arow0 = lds + (wm * 32 + fr) * 272;
  const char* arow1 = arow0 + 16 * 272;
  const int   ksh   = kc * 8;

  floatx4 acc[2][5];
#pragma unroll
  for (int i = 0; i < 2; ++i)
#pragma unroll
    for (int n = 0; n < 5; ++n) acc[i][n] = (floatx4)0.0f;

  short8 s0[5], s1[5], s2[5], s3[5], s4[5];

#define LOADB(TT, SET) {                                  \
    const char* p_ = bsrc + (size_t)(TT) * 20480;         \
    SET[0] = *(const short8*)(p_);                        \
    SET[1] = *(const short8*)(p_ + 1024);                 \
    SET[2] = *(const short8*)(p_ + 2048);                 \
    SET[3] = *(const short8*)(p_ + 3072);                 \
    SET[4] = *(const short8*)(p_ + 4096);                 \
  }

#define AFRAG(WORD, DST) {                                \
    unsigned x_ = ((WORD) >> ksh) & 0xFFu;                \
    unsigned y_ = x_ | (x_ << 15);                        \
    union { unsigned u[4]; short8 s; } c_;                \
    c_.u[0] = (y_        & 0x10001u) * 0x3F80u;           \
    c_.u[1] = ((y_ >> 2) & 0x10001u) * 0x3F80u;           \
    c_.u[2] = ((y_ >> 4) & 0x10001u) * 0x3F80u;           \
    c_.u[3] = ((y_ >> 6) & 0x10001u) * 0x3F80u;           \
    DST = c_.s;                                           \
  }

#define COMPUTE(W0, W1, SET) {                                                   \
    short8 af0_, af1_;                                                           \
    AFRAG(W0, af0_);                                                             \
    AFRAG(W1, af1_);                                                             \
    _Pragma("unroll")                                                            \
    for (int nf = 0; nf < 5; ++nf) {                                             \
      acc[0][nf] = __builtin_amdgcn_mfma_f32_16x16x32_bf16(af0_, SET[nf], acc[0][nf], 0, 0, 0); \
      acc[1][nf] = __builtin_amdgcn_mfma_f32_16x16x32_bf16(af1_, SET[nf], acc[1][nf], 0, 0, 0); \
    }                                                                            \
  }

#define PHASE(TT, CSET, LSET) {                                      \
    LOADB((TT) + 4, LSET);                                           \
    unsigned an0_ = *(const unsigned*)(arow0 + ((TT) + 1) * 4);      \
    unsigned an1_ = *(const unsigned*)(arow1 + ((TT) + 1) * 4);      \
    asm volatile("s_waitcnt vmcnt(20)" ::: "memory");                \
    COMPUTE(aw0, aw1, CSET);                                         \
    aw0 = an0_; aw1 = an1_;                                          \
  }

#define TAILPHASE(TT, GATE, CSET) {                                  \
    unsigned an0_ = *(const unsigned*)(arow0 + ((TT) + 1) * 4);      \
    unsigned an1_ = *(const unsigned*)(arow1 + ((TT) + 1) * 4);      \
    asm volatile("s_waitcnt vmcnt(" #GATE ")" ::: "memory");         \
    COMPUTE(aw0, aw1, CSET);                                         \
    aw0 = an0_; aw1 = an1_;                                          \
  }

  unsigned aw0 = *(const unsigned*)(arow0);
  unsigned aw1 = *(const unsigned*)(arow1);
  LOADB(0, s0); LOADB(1, s1); LOADB(2, s2); LOADB(3, s3);

#pragma unroll 1
  for (int k = 0; k < 12; ++k) {
    int t5 = k * 5;
    PHASE(t5 + 0, s0, s4);
    PHASE(t5 + 1, s1, s0);
    PHASE(t5 + 2, s2, s1);
    PHASE(t5 + 3, s3, s2);
    PHASE(t5 + 4, s4, s3);
  }
  TAILPHASE(60, 15, s0);
  TAILPHASE(61, 10, s1);
  TAILPHASE(62, 5,  s2);
  asm volatile("s_waitcnt vmcnt(0)" ::: "memory");
  COMPUTE(aw0, aw1, s3);

  // epilogue: den = col 256 -> wn==3, nf==1, fr==0
  float* denL = (float*)(lds + 64 * 272);
  const int q = L >> 4;
  if (wn == 3 && fr == 0) {
#pragma unroll
    for (int mf = 0; mf < 2; ++mf)
#pragma unroll
      for (int jj = 0; jj < 4; ++jj)
        denL[wm * 32 + mf * 16 + q * 4 + jj] = acc[mf][1][jj];
  }
  __syncthreads();
  float invd[2][4];
#pragma unroll
  for (int mf = 0; mf < 2; ++mf)
#pragma unroll
    for (int jj = 0; jj < 4; ++jj)
      invd[mf][jj] = 1.0f / denL[wm * 32 + mf * 16 + q * 4 + jj];
#pragma unroll
  for (int mf = 0; mf < 2; ++mf) {
#pragma unroll
    for (int nf = 0; nf < 5; ++nf) {
      int col = wn * 80 + nf * 16 + fr;
      if (col < 256) {
#pragma unroll
        for (int jj = 0; jj < 4; ++jj) {
          int row = wm * 32 + mf * 16 + q * 4 + jj;
          float v = acc[mf][nf][jj] * invd[mf][jj];
          v = (v > 0.0f) ? v : expm1f(v);
          out[((size_t)b * 2048 + i0 + row) * 256 + col] = v;
        }
      }
    }
  }
#undef PHASE
#undef TAILPHASE
#undef COMPUTE
#undef AFRAG
#undef LOADB
}

extern "C" void kernel_launch(void* const* d_in, const int* in_sizes, int n_in,
                              void* d_out, int out_size, void* d_ws, size_t ws_size,
                              hipStream_t stream) {
  const float* h   = (const float*)d_in[0];
  const int*   adj = (const int*)d_in[1];
  const float* W   = (const float*)d_in[2];
  const float* a   = (const float*)d_in[3];
  float* out = (float*)d_out;

  char* ws = (char*)d_ws;
  if (ws_size < 19071232) return;
  unsigned short* Whb = (unsigned short*)ws;              //  8,388,608 B
  float* g            = (float*)(ws + 8388608);           //     65,536 B
  float* Mb           = (float*)(ws + 8454144);           //        256 B
  unsigned short* Bt  = (unsigned short*)(ws + 8454400);  // 10,485,760 B
  unsigned short* Wt  = (unsigned short*)(ws + 18940160); //    131,072 B

  hipMemsetAsync(g, 0, 65536, stream);
  wt_conv  <<<256, 256, 0, stream>>>(W, Wt);
  wh_mfma  <<<512, 256, 0, stream>>>(h, Wt, Whb, a, g);
  batch_max<<<8,   256, 0, stream>>>(g, Mb);
  build_bt <<<256, 256, 0, stream>>>(Whb, g, Mb, Bt);
  gat_main <<<256, 512, 0, stream>>>(adj, Bt, out);
}

// Round 13
// 103.259 us; speedup vs baseline: 1.4428x; 1.1036x over previous
//
#include <hip/hip_runtime.h>
#include <math.h>

using short8   = __attribute__((ext_vector_type(8))) short;
using floatx4  = __attribute__((ext_vector_type(4))) float;
using ushort4v = __attribute__((ext_vector_type(4))) unsigned short;

__device__ __forceinline__ unsigned short f2bf(float x) {
  union { float f; unsigned u; } v; v.f = x;
  unsigned r = (v.u + 0x7FFFu + ((v.u >> 16) & 1u)) >> 16;
  return (unsigned short)r;
}
__device__ __forceinline__ float bf2f(unsigned short u) {
  union { unsigned u; float f; } v; v.u = ((unsigned)u) << 16;
  return v.f;
}
__device__ __forceinline__ short8 cvt8(const float* p) {
  float4 v0 = *(const float4*)p;
  float4 v1 = *(const float4*)(p + 4);
  short8 r;
  r[0] = (short)f2bf(v0.x); r[1] = (short)f2bf(v0.y);
  r[2] = (short)f2bf(v0.z); r[3] = (short)f2bf(v0.w);
  r[4] = (short)f2bf(v1.x); r[5] = (short)f2bf(v1.y);
  r[6] = (short)f2bf(v1.z); r[7] = (short)f2bf(v1.w);
  return r;
}

// ---------------- K0a: pack adj int32 -> bit per element (coalesced) ----------------
__global__ __launch_bounds__(256) void adj_pack(
    const int* __restrict__ adj, unsigned* __restrict__ pk) {
  size_t tid = (size_t)blockIdx.x * 256 + threadIdx.x;   // 0..1,048,575
  const int* src = adj + tid * 32;
  unsigned r = 0;
#pragma unroll
  for (int q = 0; q < 8; ++q) {
    int4 v = *(const int4*)(src + q * 4);
    r |= ((unsigned)v.x << (4 * q)) | ((unsigned)v.y << (4 * q + 1)) |
         ((unsigned)v.z << (4 * q + 2)) | ((unsigned)v.w << (4 * q + 3));
  }
  pk[tid] = r;
}

// ---------------- K0b: W (f32 [k][n]) -> Wt bf16 tile layout ----------------
__global__ __launch_bounds__(256) void wt_conv(
    const float* __restrict__ W, unsigned short* __restrict__ Wt) {
  int c = blockIdx.x;
  int k = threadIdx.x;
  int kt = k >> 5;
  Wt[(size_t)(kt * 256 + c) * 32 + (k & 31)] = f2bf(W[(size_t)k * 256 + c]);
}

// ---------------- K1: Wh = h @ W via bf16 MFMA (f32 accum) + fused g-dot ----------------
__global__ __launch_bounds__(256) void wh_mfma(
    const float* __restrict__ h, const unsigned short* __restrict__ Wt,
    unsigned short* __restrict__ Whb, const float* __restrict__ a,
    float* __restrict__ g) {
  const int m0 = blockIdx.x * 32;
  const int t  = threadIdx.x;
  const int w  = t >> 6, L = t & 63;
  const int fr = L & 15, kc = L >> 4;

  const float* hrow0 = h + (size_t)(m0 + fr) * 256;
  const float* hrow1 = h + (size_t)(m0 + 16 + fr) * 256;

  floatx4 acc[2][4];
#pragma unroll
  for (int i = 0; i < 2; ++i)
#pragma unroll
    for (int n = 0; n < 4; ++n) acc[i][n] = (floatx4)0.0f;

#pragma unroll
  for (int kt = 0; kt < 8; ++kt) {
    short8 a0 = cvt8(hrow0 + kt * 32 + kc * 8);
    short8 a1 = cvt8(hrow1 + kt * 32 + kc * 8);
#pragma unroll
    for (int nf = 0; nf < 4; ++nf) {
      int c = w * 64 + nf * 16 + fr;
      short8 bf = *(const short8*)(Wt + (size_t)(kt * 256 + c) * 32 + kc * 8);
      acc[0][nf] = __builtin_amdgcn_mfma_f32_16x16x32_bf16(a0, bf, acc[0][nf], 0, 0, 0);
      acc[1][nf] = __builtin_amdgcn_mfma_f32_16x16x32_bf16(a1, bf, acc[1][nf], 0, 0, 0);
    }
  }

  const int q = L >> 4;
  float a2v[4];
#pragma unroll
  for (int nf = 0; nf < 4; ++nf) a2v[nf] = a[256 + w * 64 + nf * 16 + fr];
#pragma unroll
  for (int mf = 0; mf < 2; ++mf) {
    float p[4] = {0.f, 0.f, 0.f, 0.f};
#pragma unroll
    for (int nf = 0; nf < 4; ++nf) {
#pragma unroll
      for (int jj = 0; jj < 4; ++jj) {
        int row = m0 + mf * 16 + q * 4 + jj;
        Whb[(size_t)row * 256 + w * 64 + nf * 16 + fr] = f2bf(acc[mf][nf][jj]);
        p[jj] += acc[mf][nf][jj] * a2v[nf];
      }
    }
#pragma unroll
    for (int jj = 0; jj < 4; ++jj) {
#pragma unroll
      for (int off = 1; off < 16; off <<= 1) p[jj] += __shfl_xor(p[jj], off);
      if (fr == 0) atomicAdd(&g[m0 + mf * 16 + q * 4 + jj], p[jj]);
    }
  }
}

// ---------------- K2b: per-batch max of g ----------------
__global__ __launch_bounds__(256) void batch_max(
    const float* __restrict__ g, float* __restrict__ Mb) {
  __shared__ float red[4];
  int b = blockIdx.x, t = threadIdx.x;
  float m = -1e30f;
  for (int i = t; i < 2048; i += 256) m = fmaxf(m, g[(size_t)b * 2048 + i]);
#pragma unroll
  for (int off = 32; off > 0; off >>= 1) m = fmaxf(m, __shfl_xor(m, off));
  if ((t & 63) == 0) red[t >> 6] = m;
  __syncthreads();
  if (t == 0) Mb[b] = fmaxf(fmaxf(red[0], red[1]), fmaxf(red[2], red[3]));
}

// ---------------- K2c: tile-contiguous B (72-short padded rows) ----------------
__global__ __launch_bounds__(256) void build_bt(
    const unsigned short* __restrict__ Whb, const float* __restrict__ g,
    const float* __restrict__ Mb, unsigned short* __restrict__ Bt) {
  __shared__ __align__(16) unsigned short tile[320 * 72];
  const int blk = blockIdx.x;
  const int b   = blk >> 5;
  const int j0  = (blk & 31) * 64;
  const int kt_base = (blk & 31) * 2;
  const int t   = threadIdx.x;
  const int j   = t & 63;
  const int q0  = t >> 6;
  const int row = b * 2048 + j0 + j;
  const float s = expf(g[row] - Mb[b]);
  for (int q = q0; q < 64; q += 4) {
    ushort4v wv = *(const ushort4v*)&Whb[(size_t)row * 256 + q * 4];
    int c = q * 4;
    tile[(c + 0) * 72 + j] = f2bf(s * bf2f(wv[0]));
    tile[(c + 1) * 72 + j] = f2bf(s * bf2f(wv[1]));
    tile[(c + 2) * 72 + j] = f2bf(s * bf2f(wv[2]));
    tile[(c + 3) * 72 + j] = f2bf(s * bf2f(wv[3]));
  }
  if (q0 == 0) tile[256 * 72 + j] = f2bf(s);
  for (int z = t; z < 63 * 64; z += 256) {
    int c = 257 + (z >> 6);
    tile[c * 72 + (z & 63)] = 0;
  }
  __syncthreads();
#pragma unroll
  for (int p = 0; p < 10; ++p) {
    int id = t + 256 * p;
    int c = id >> 3, off = id & 7;
    int kt_l = off >> 2, slot = off & 3;
    size_t dst = ((size_t)((b * 64 + kt_base + kt_l) * 320 + c)) * 64 + (slot << 4);
    *(int4*)((char*)Bt + dst) = *(const int4*)&tile[c * 72 + off * 8];
  }
}

// ---------------- K3: [num|den] = adj @ Bt^T (R8/R9-proven, pk input) ----------------
// grid 256 (b=bid&7 XCD-pinned), 512 threads = 8 waves (2 row-grp x 4 col-grp).
// BM=64, BN=320. A = packed bits in LDS (coalesced 16KB prologue from pk).
// B direct global->reg, 5 named sets, vmcnt(20) gates, launch_bounds(512,2).
__global__ __launch_bounds__(512, 2) void gat_main(
    const unsigned* __restrict__ pk, const unsigned short* __restrict__ Bt,
    float* __restrict__ out) {
  __shared__ __align__(16) char lds[64 * 272 + 256];  // A bits (stride 272) + den
  const int bid = blockIdx.x;
  const int b   = bid & 7;
  const int rb  = bid >> 3;
  const int i0  = rb * 64;
  const int tid = threadIdx.x;
  const int w   = tid >> 6, L = tid & 63;
  const int wm  = w >> 2, wn = w & 3;     // row-group, col-group
  const int fr  = L & 15, kc = L >> 4;

  // prologue: stage 64 rows x 256B of packed bits, row stride 272 (coalesced)
  {
    int r = tid >> 3, seg = tid & 7;
    const char* src = (const char*)pk + ((size_t)(b * 2048 + i0 + r) * 256 + seg * 32);
    char* dst = lds + r * 272 + seg * 32;
    *(int4*)(dst)      = *(const int4*)(src);
    *(int4*)(dst + 16) = *(const int4*)(src + 16);
  }
  __syncthreads();

  const char* bsrc = (const char*)Bt + (size_t)b * 1310720
                   + (size_t)(wn * 80 + fr) * 64 + (kc << 4);
  const char* arow0 = lds + (wm * 32 + fr) * 272;
  const char* arow1 = arow0 + 16 * 272;
  const int   ksh   = kc * 8;

  floatx4 acc[2][5];
#pragma unroll
  for (int i = 0; i < 2; ++i)
#pragma unroll
    for (int n = 0; n < 5; ++n) acc[i][n] = (floatx4)0.0f;

  short8 s0[5], s1[5], s2[5], s3[5], s4[5];

#define LOADB(TT, SET) {                                  \
    const char* p_ = bsrc + (size_t)(TT) * 20480;         \
    SET[0] = *(const short8*)(p_);                        \
    SET[1] = *(const short8*)(p_ + 1024);                 \
    SET[2] = *(const short8*)(p_ + 2048);                 \
    SET[3] = *(const short8*)(p_ + 3072);                 \
    SET[4] = *(const short8*)(p_ + 4096);                 \
  }

  // bit->bf16 expand: y = x | x<<15; dword j = ((y>>2j) & 0x10001) * 0x3F80
#define AFRAG(WORD, DST) {                                \
    unsigned x_ = ((WORD) >> ksh) & 0xFFu;                \
    unsigned y_ = x_ | (x_ << 15);                        \
    union { unsigned u[4]; short8 s; } c_;                \
    c_.u[0] = (y_        & 0x10001u) * 0x3F80u;           \
    c_.u[1] = ((y_ >> 2) & 0x10001u) * 0x3F80u;           \
    c_.u[2] = ((y_ >> 4) & 0x10001u) * 0x3F80u;           \
    c_.u[3] = ((y_ >> 6) & 0x10001u) * 0x3F80u;           \
    DST = c_.s;                                           \
  }

#define COMPUTE(W0, W1, SET) {                                                   \
    short8 af0_, af1_;                                                           \
    AFRAG(W0, af0_);                                                             \
    AFRAG(W1, af1_);                                                             \
    _Pragma("unroll")                                                            \
    for (int nf = 0; nf < 5; ++nf) {                                             \
      acc[0][nf] = __builtin_amdgcn_mfma_f32_16x16x32_bf16(af0_, SET[nf], acc[0][nf], 0, 0, 0); \
      acc[1][nf] = __builtin_amdgcn_mfma_f32_16x16x32_bf16(af1_, SET[nf], acc[1][nf], 0, 0, 0); \
    }                                                                            \
  }

#define PHASE(TT, CSET, LSET) {                                      \
    LOADB((TT) + 4, LSET);                                           \
    unsigned an0_ = *(const unsigned*)(arow0 + ((TT) + 1) * 4);      \
    unsigned an1_ = *(const unsigned*)(arow1 + ((TT) + 1) * 4);      \
    asm volatile("s_waitcnt vmcnt(20)" ::: "memory");                \
    COMPUTE(aw0, aw1, CSET);                                         \
    aw0 = an0_; aw1 = an1_;                                          \
  }

#define TAILPHASE(TT, GATE, CSET) {                                  \
    unsigned an0_ = *(const unsigned*)(arow0 + ((TT) + 1) * 4);      \
    unsigned an1_ = *(const unsigned*)(arow1 + ((TT) + 1) * 4);      \
    asm volatile("s_waitcnt vmcnt(" #GATE ")" ::: "memory");         \
    COMPUTE(aw0, aw1, CSET);                                         \
    aw0 = an0_; aw1 = an1_;                                          \
  }

  unsigned aw0 = *(const unsigned*)(arow0);
  unsigned aw1 = *(const unsigned*)(arow1);
  LOADB(0, s0); LOADB(1, s1); LOADB(2, s2); LOADB(3, s3);

#pragma unroll 1
  for (int k = 0; k < 12; ++k) {
    int t5 = k * 5;
    PHASE(t5 + 0, s0, s4);
    PHASE(t5 + 1, s1, s0);
    PHASE(t5 + 2, s2, s1);
    PHASE(t5 + 3, s3, s2);
    PHASE(t5 + 4, s4, s3);
  }
  TAILPHASE(60, 15, s0);
  TAILPHASE(61, 10, s1);
  TAILPHASE(62, 5,  s2);
  asm volatile("s_waitcnt vmcnt(0)" ::: "memory");
  COMPUTE(aw0, aw1, s3);

  // epilogue: den = col 256 -> wn==3, nf==1, fr==0
  float* denL = (float*)(lds + 64 * 272);
  const int q = L >> 4;
  if (wn == 3 && fr == 0) {
#pragma unroll
    for (int mf = 0; mf < 2; ++mf)
#pragma unroll
      for (int jj = 0; jj < 4; ++jj)
        denL[wm * 32 + mf * 16 + q * 4 + jj] = acc[mf][1][jj];
  }
  __syncthreads();
  float invd[2][4];
#pragma unroll
  for (int mf = 0; mf < 2; ++mf)
#pragma unroll
    for (int jj = 0; jj < 4; ++jj)
      invd[mf][jj] = 1.0f / denL[wm * 32 + mf * 16 + q * 4 + jj];
#pragma unroll
  for (int mf = 0; mf < 2; ++mf) {
#pragma unroll
    for (int nf = 0; nf < 5; ++nf) {
      int col = wn * 80 + nf * 16 + fr;
      if (col < 256) {
#pragma unroll
        for (int jj = 0; jj < 4; ++jj) {
          int row = wm * 32 + mf * 16 + q * 4 + jj;
          float v = acc[mf][nf][jj] * invd[mf][jj];
          v = (v > 0.0f) ? v : expm1f(v);
          out[((size_t)b * 2048 + i0 + row) * 256 + col] = v;
        }
      }
    }
  }
#undef PHASE
#undef TAILPHASE
#undef COMPUTE
#undef AFRAG
#undef LOADB
}

extern "C" void kernel_launch(void* const* d_in, const int* in_sizes, int n_in,
                              void* d_out, int out_size, void* d_ws, size_t ws_size,
                              hipStream_t stream) {
  const float* h   = (const float*)d_in[0];
  const int*   adj = (const int*)d_in[1];
  const float* W   = (const float*)d_in[2];
  const float* a   = (const float*)d_in[3];
  float* out = (float*)d_out;

  char* ws = (char*)d_ws;
  if (ws_size < 23265536) return;
  unsigned short* Whb = (unsigned short*)ws;              //  8,388,608 B
  float* g            = (float*)(ws + 8388608);           //     65,536 B
  float* Mb           = (float*)(ws + 8454144);           //        256 B
  unsigned short* Bt  = (unsigned short*)(ws + 8454400);  // 10,485,760 B
  unsigned short* Wt  = (unsigned short*)(ws + 18940160); //    131,072 B
  unsigned* pk        = (unsigned*)(ws + 19071232);       //  4,194,304 B

  hipMemsetAsync(g, 0, 65536, stream);
  adj_pack <<<4096, 256, 0, stream>>>(adj, pk);
  wt_conv  <<<256,  256, 0, stream>>>(W, Wt);
  wh_mfma  <<<512,  256, 0, stream>>>(h, Wt, Whb, a, g);
  batch_max<<<8,    256, 0, stream>>>(g, Mb);
  build_bt <<<256,  256, 0, stream>>>(Whb, g, Mb, Bt);
  gat_main <<<256,  512, 0, stream>>>(pk, Bt, out);
}

// Round 14
// 103.140 us; speedup vs baseline: 1.4444x; 1.0012x over previous
//
#include <hip/hip_runtime.h>
#include <math.h>

using short8   = __attribute__((ext_vector_type(8))) short;
using floatx4  = __attribute__((ext_vector_type(4))) float;
using ushort4v = __attribute__((ext_vector_type(4))) unsigned short;

__device__ __forceinline__ unsigned short f2bf(float x) {
  union { float f; unsigned u; } v; v.f = x;
  unsigned r = (v.u + 0x7FFFu + ((v.u >> 16) & 1u)) >> 16;
  return (unsigned short)r;
}
__device__ __forceinline__ float bf2f(unsigned short u) {
  union { unsigned u; float f; } v; v.u = ((unsigned)u) << 16;
  return v.f;
}
__device__ __forceinline__ short8 cvt8(const float* p) {
  float4 v0 = *(const float4*)p;
  float4 v1 = *(const float4*)(p + 4);
  short8 r;
  r[0] = (short)f2bf(v0.x); r[1] = (short)f2bf(v0.y);
  r[2] = (short)f2bf(v0.z); r[3] = (short)f2bf(v0.w);
  r[4] = (short)f2bf(v1.x); r[5] = (short)f2bf(v1.y);
  r[6] = (short)f2bf(v1.z); r[7] = (short)f2bf(v1.w);
  return r;
}

// ---------------- K0a: pack adj int32 -> bit per element (coalesced) ----------------
__global__ __launch_bounds__(256) void adj_pack(
    const int* __restrict__ adj, unsigned* __restrict__ pk) {
  size_t tid = (size_t)blockIdx.x * 256 + threadIdx.x;   // 0..1,048,575
  const int* src = adj + tid * 32;
  unsigned r = 0;
#pragma unroll
  for (int q = 0; q < 8; ++q) {
    int4 v = *(const int4*)(src + q * 4);
    r |= ((unsigned)v.x << (4 * q)) | ((unsigned)v.y << (4 * q + 1)) |
         ((unsigned)v.z << (4 * q + 2)) | ((unsigned)v.w << (4 * q + 3));
  }
  pk[tid] = r;
}

// ---------------- K0b: W (f32 [k][n]) -> Wt bf16 tile layout ----------------
__global__ __launch_bounds__(256) void wt_conv(
    const float* __restrict__ W, unsigned short* __restrict__ Wt) {
  int c = blockIdx.x;
  int k = threadIdx.x;
  int kt = k >> 5;
  Wt[(size_t)(kt * 256 + c) * 32 + (k & 31)] = f2bf(W[(size_t)k * 256 + c]);
}

// ---------------- K1: Wh = h @ W via bf16 MFMA (f32 accum) + fused g-dot ----------------
__global__ __launch_bounds__(256) void wh_mfma(
    const float* __restrict__ h, const unsigned short* __restrict__ Wt,
    unsigned short* __restrict__ Whb, const float* __restrict__ a,
    float* __restrict__ g) {
  const int m0 = blockIdx.x * 32;
  const int t  = threadIdx.x;
  const int w  = t >> 6, L = t & 63;
  const int fr = L & 15, kc = L >> 4;

  const float* hrow0 = h + (size_t)(m0 + fr) * 256;
  const float* hrow1 = h + (size_t)(m0 + 16 + fr) * 256;

  floatx4 acc[2][4];
#pragma unroll
  for (int i = 0; i < 2; ++i)
#pragma unroll
    for (int n = 0; n < 4; ++n) acc[i][n] = (floatx4)0.0f;

#pragma unroll
  for (int kt = 0; kt < 8; ++kt) {
    short8 a0 = cvt8(hrow0 + kt * 32 + kc * 8);
    short8 a1 = cvt8(hrow1 + kt * 32 + kc * 8);
#pragma unroll
    for (int nf = 0; nf < 4; ++nf) {
      int c = w * 64 + nf * 16 + fr;
      short8 bf = *(const short8*)(Wt + (size_t)(kt * 256 + c) * 32 + kc * 8);
      acc[0][nf] = __builtin_amdgcn_mfma_f32_16x16x32_bf16(a0, bf, acc[0][nf], 0, 0, 0);
      acc[1][nf] = __builtin_amdgcn_mfma_f32_16x16x32_bf16(a1, bf, acc[1][nf], 0, 0, 0);
    }
  }

  const int q = L >> 4;
  float a2v[4];
#pragma unroll
  for (int nf = 0; nf < 4; ++nf) a2v[nf] = a[256 + w * 64 + nf * 16 + fr];
#pragma unroll
  for (int mf = 0; mf < 2; ++mf) {
    float p[4] = {0.f, 0.f, 0.f, 0.f};
#pragma unroll
    for (int nf = 0; nf < 4; ++nf) {
#pragma unroll
      for (int jj = 0; jj < 4; ++jj) {
        int row = m0 + mf * 16 + q * 4 + jj;
        Whb[(size_t)row * 256 + w * 64 + nf * 16 + fr] = f2bf(acc[mf][nf][jj]);
        p[jj] += acc[mf][nf][jj] * a2v[nf];
      }
    }
#pragma unroll
    for (int jj = 0; jj < 4; ++jj) {
#pragma unroll
      for (int off = 1; off < 16; off <<= 1) p[jj] += __shfl_xor(p[jj], off);
      if (fr == 0) atomicAdd(&g[m0 + mf * 16 + q * 4 + jj], p[jj]);
    }
  }
}

// ---------------- K2b: per-batch max of g ----------------
__global__ __launch_bounds__(256) void batch_max(
    const float* __restrict__ g, float* __restrict__ Mb) {
  __shared__ float red[4];
  int b = blockIdx.x, t = threadIdx.x;
  float m = -1e30f;
  for (int i = t; i < 2048; i += 256) m = fmaxf(m, g[(size_t)b * 2048 + i]);
#pragma unroll
  for (int off = 32; off > 0; off >>= 1) m = fmaxf(m, __shfl_xor(m, off));
  if ((t & 63) == 0) red[t >> 6] = m;
  __syncthreads();
  if (t == 0) Mb[b] = fmaxf(fmaxf(red[0], red[1]), fmaxf(red[2], red[3]));
}

// ---------------- K2c: tile-contiguous B (72-short padded rows) ----------------
__global__ __launch_bounds__(256) void build_bt(
    const unsigned short* __restrict__ Whb, const float* __restrict__ g,
    const float* __restrict__ Mb, unsigned short* __restrict__ Bt) {
  __shared__ __align__(16) unsigned short tile[320 * 72];
  const int blk = blockIdx.x;
  const int b   = blk >> 5;
  const int j0  = (blk & 31) * 64;
  const int kt_base = (blk & 31) * 2;
  const int t   = threadIdx.x;
  const int j   = t & 63;
  const int q0  = t >> 6;
  const int row = b * 2048 + j0 + j;
  const float s = expf(g[row] - Mb[b]);
  for (int q = q0; q < 64; q += 4) {
    ushort4v wv = *(const ushort4v*)&Whb[(size_t)row * 256 + q * 4];
    int c = q * 4;
    tile[(c + 0) * 72 + j] = f2bf(s * bf2f(wv[0]));
    tile[(c + 1) * 72 + j] = f2bf(s * bf2f(wv[1]));
    tile[(c + 2) * 72 + j] = f2bf(s * bf2f(wv[2]));
    tile[(c + 3) * 72 + j] = f2bf(s * bf2f(wv[3]));
  }
  if (q0 == 0) tile[256 * 72 + j] = f2bf(s);
  for (int z = t; z < 63 * 64; z += 256) {
    int c = 257 + (z >> 6);
    tile[c * 72 + (z & 63)] = 0;
  }
  __syncthreads();
#pragma unroll
  for (int p = 0; p < 10; ++p) {
    int id = t + 256 * p;
    int c = id >> 3, off = id & 7;
    int kt_l = off >> 2, slot = off & 3;
    size_t dst = ((size_t)((b * 64 + kt_base + kt_l) * 320 + c)) * 64 + (slot << 4);
    *(int4*)((char*)Bt + dst) = *(const int4*)&tile[c * 72 + off * 8];
  }
}

// ---------------- K3: [num|den] = adj @ Bt^T ----------------
// grid 256 (b=bid&7 XCD-pinned), 512 threads = 8 waves (2 row-grp x 4 col-grp).
// BM=64, BN=320. A = packed bits in LDS (coalesced 16KB prologue from pk).
// B direct global->reg, 5 named sets, vmcnt(20) gates.
// __launch_bounds__(512, 1): 256-VGPR cap so all 5 sets stay LIVE (R13 had
// (512,2) -> 128-VGPR cap -> VGPR 96 -> pipeline collapsed to ~1-deep).
__global__ __launch_bounds__(512, 1) void gat_main(
    const unsigned* __restrict__ pk, const unsigned short* __restrict__ Bt,
    float* __restrict__ out) {
  __shared__ __align__(16) char lds[64 * 272 + 256];  // A bits (stride 272) + den
  const int bid = blockIdx.x;
  const int b   = bid & 7;
  const int rb  = bid >> 3;
  const int i0  = rb * 64;
  const int tid = threadIdx.x;
  const int w   = tid >> 6, L = tid & 63;
  const int wm  = w >> 2, wn = w & 3;     // row-group, col-group
  const int fr  = L & 15, kc = L >> 4;

  // prologue: stage 64 rows x 256B of packed bits, row stride 272 (coalesced)
  {
    int r = tid >> 3, seg = tid & 7;
    const char* src = (const char*)pk + ((size_t)(b * 2048 + i0 + r) * 256 + seg * 32);
    char* dst = lds + r * 272 + seg * 32;
    *(int4*)(dst)      = *(const int4*)(src);
    *(int4*)(dst + 16) = *(const int4*)(src + 16);
  }
  __syncthreads();

  const char* bsrc = (const char*)Bt + (size_t)b * 1310720
                   + (size_t)(wn * 80 + fr) * 64 + (kc << 4);
  const char* arow0 = lds + (wm * 32 + fr) * 272;
  const char* arow1 = arow0 + 16 * 272;
  const int   ksh   = kc * 8;

  floatx4 acc[2][5];
#pragma unroll
  for (int i = 0; i < 2; ++i)
#pragma unroll
    for (int n = 0; n < 5; ++n) acc[i][n] = (floatx4)0.0f;

  short8 s0[5], s1[5], s2[5], s3[5], s4[5];

#define LOADB(TT, SET) {                                  \
    const char* p_ = bsrc + (size_t)(TT) * 20480;         \
    SET[0] = *(const short8*)(p_);                        \
    SET[1] = *(const short8*)(p_ + 1024);                 \
    SET[2] = *(const short8*)(p_ + 2048);                 \
    SET[3] = *(const short8*)(p_ + 3072);                 \
    SET[4] = *(const short8*)(p_ + 4096);                 \
  }

  // bit->bf16 expand: y = x | x<<15; dword j = ((y>>2j) & 0x10001) * 0x3F80
#define AFRAG(WORD, DST) {                                \
    unsigned x_ = ((WORD) >> ksh) & 0xFFu;                \
    unsigned y_ = x_ | (x_ << 15);                        \
    union { unsigned u[4]; short8 s; } c_;                \
    c_.u[0] = (y_        & 0x10001u) * 0x3F80u;           \
    c_.u[1] = ((y_ >> 2) & 0x10001u) * 0x3F80u;           \
    c_.u[2] = ((y_ >> 4) & 0x10001u) * 0x3F80u;           \
    c_.u[3] = ((y_ >> 6) & 0x10001u) * 0x3F80u;           \
    DST = c_.s;                                           \
  }

#define COMPUTE(W0, W1, SET) {                                                   \
    short8 af0_, af1_;                                                           \
    AFRAG(W0, af0_);                                                             \
    AFRAG(W1, af1_);                                                             \
    _Pragma("unroll")                                                            \
    for (int nf = 0; nf < 5; ++nf) {                                             \
      acc[0][nf] = __builtin_amdgcn_mfma_f32_16x16x32_bf16(af0_, SET[nf], acc[0][nf], 0, 0, 0); \
      acc[1][nf] = __builtin_amdgcn_mfma_f32_16x16x32_bf16(af1_, SET[nf], acc[1][nf], 0, 0, 0); \
    }                                                                            \
  }

#define PHASE(TT, CSET, LSET) {                                      \
    LOADB((TT) + 4, LSET);                                           \
    unsigned an0_ = *(const unsigned*)(arow0 + ((TT) + 1) * 4);      \
    unsigned an1_ = *(const unsigned*)(arow1 + ((TT) + 1) * 4);      \
    asm volatile("s_waitcnt vmcnt(20)" ::: "memory");                \
    COMPUTE(aw0, aw1, CSET);                                         \
    aw0 = an0_; aw1 = an1_;                                          \
  }

#define TAILPHASE(TT, GATE, CSET) {                                  \
    unsigned an0_ = *(const unsigned*)(arow0 + ((TT) + 1) * 4);      \
    unsigned an1_ = *(const unsigned*)(arow1 + ((TT) + 1) * 4);      \
    asm volatile("s_waitcnt vmcnt(" #GATE ")" ::: "memory");         \
    COMPUTE(aw0, aw1, CSET);                                         \
    aw0 = an0_; aw1 = an1_;                                          \
  }

  unsigned aw0 = *(const unsigned*)(arow0);
  unsigned aw1 = *(const unsigned*)(arow1);
  LOADB(0, s0); LOADB(1, s1); LOADB(2, s2); LOADB(3, s3);

#pragma unroll 1
  for (int k = 0; k < 12; ++k) {
    int t5 = k * 5;
    PHASE(t5 + 0, s0, s4);
    PHASE(t5 + 1, s1, s0);
    PHASE(t5 + 2, s2, s1);
    PHASE(t5 + 3, s3, s2);
    PHASE(t5 + 4, s4, s3);
  }
  TAILPHASE(60, 15, s0);
  TAILPHASE(61, 10, s1);
  TAILPHASE(62, 5,  s2);
  asm volatile("s_waitcnt vmcnt(0)" ::: "memory");
  COMPUTE(aw0, aw1, s3);

  // epilogue: den = col 256 -> wn==3, nf==1, fr==0
  float* denL = (float*)(lds + 64 * 272);
  const int q = L >> 4;
  if (wn == 3 && fr == 0) {
#pragma unroll
    for (int mf = 0; mf < 2; ++mf)
#pragma unroll
      for (int jj = 0; jj < 4; ++jj)
        denL[wm * 32 + mf * 16 + q * 4 + jj] = acc[mf][1][jj];
  }
  __syncthreads();
  float invd[2][4];
#pragma unroll
  for (int mf = 0; mf < 2; ++mf)
#pragma unroll
    for (int jj = 0; jj < 4; ++jj)
      invd[mf][jj] = 1.0f / denL[wm * 32 + mf * 16 + q * 4 + jj];
#pragma unroll
  for (int mf = 0; mf < 2; ++mf) {
#pragma unroll
    for (int nf = 0; nf < 5; ++nf) {
      int col = wn * 80 + nf * 16 + fr;
      if (col < 256) {
#pragma unroll
        for (int jj = 0; jj < 4; ++jj) {
          int row = wm * 32 + mf * 16 + q * 4 + jj;
          float v = acc[mf][nf][jj] * invd[mf][jj];
          v = (v > 0.0f) ? v : expm1f(v);
          out[((size_t)b * 2048 + i0 + row) * 256 + col] = v;
        }
      }
    }
  }
#undef PHASE
#undef TAILPHASE
#undef COMPUTE
#undef AFRAG
#undef LOADB
}

extern "C" void kernel_launch(void* const* d_in, const int* in_sizes, int n_in,
                              void* d_out, int out_size, void* d_ws, size_t ws_size,
                              hipStream_t stream) {
  const float* h   = (const float*)d_in[0];
  const int*   adj = (const int*)d_in[1];
  const float* W   = (const float*)d_in[2];
  const float* a   = (const float*)d_in[3];
  float* out = (float*)d_out;

  char* ws = (char*)d_ws;
  if (ws_size < 23265536) return;
  unsigned short* Whb = (unsigned short*)ws;              //  8,388,608 B
  float* g            = (float*)(ws + 8388608);           //     65,536 B
  float* Mb           = (float*)(ws + 8454144);           //        256 B
  unsigned short* Bt  = (unsigned short*)(ws + 8454400);  // 10,485,760 B
  unsigned short* Wt  = (unsigned short*)(ws + 18940160); //    131,072 B
  unsigned* pk        = (unsigned*)(ws + 19071232);       //  4,194,304 B

  hipMemsetAsync(g, 0, 65536, stream);
  adj_pack <<<4096, 256, 0, stream>>>(adj, pk);
  wt_conv  <<<256,  256, 0, stream>>>(W, Wt);
  wh_mfma  <<<512,  256, 0, stream>>>(h, Wt, Whb, a, g);
  batch_max<<<8,    256, 0, stream>>>(g, Mb);
  build_bt <<<256,  256, 0, stream>>>(Whb, g, Mb, Bt);
  gat_main <<<256,  512, 0, stream>>>(pk, Bt, out);
}